// Round 1
// 2032.084 us; speedup vs baseline: 1.1915x; 1.1915x over previous
//
#include <hip/hip_runtime.h>

typedef unsigned short u16;
typedef __attribute__((ext_vector_type(8))) short short8;
typedef __attribute__((ext_vector_type(4))) float floatx4;

#define CDIM 1024
#define NB 4

__device__ __forceinline__ float bf2f(u16 u) {
  union { unsigned int i; float f; } v; v.i = ((unsigned int)u) << 16; return v.f;
}
__device__ __forceinline__ u16 f2bf(float f) {
  union { float f; unsigned int i; } v; v.f = f;
  unsigned int r = v.i + 0x7fffu + ((v.i >> 16) & 1u);
  return (u16)(r >> 16);
}
__device__ __forceinline__ float san(float f) {
  return (fabsf(f) <= 3.0e38f) ? f : 0.f;
}
// dtype-flagged input load: flag 1 = fp32, 0 = bf16
__device__ __forceinline__ float ldin(const void* p, size_t i, int f) {
  return f ? san(((const float*)p)[i]) : bf2f(((const u16*)p)[i]);
}

// async global->LDS, 16B per lane. LDS dest must be wave-uniform base + lane*16.
__device__ __forceinline__ void gload16(const u16* g, u16* l) {
  __builtin_amdgcn_global_load_lds(
      (const __attribute__((address_space(1))) void*)g,
      (__attribute__((address_space(3))) void*)l, 16, 0, 0);
}

// ---------------- per-tensor dtype sniffer ----------------
struct PtrArgs { const void* p[22]; int n[22]; };

__global__ void detect_dtypes(PtrArgs a, int* __restrict__ flags) {
  __shared__ int cnt;
  int ti = blockIdx.x;
  if (threadIdx.x == 0) cnt = 0;
  __syncthreads();
  if (ti >= 22) {
    if (threadIdx.x == 0) flags[ti] = 0;
    return;
  }
  const u16* u = (const u16*)a.p[ti];
  int m = a.n[ti]; if (m > 4096) m = 4096;
  int local = 0;
  for (int i = threadIdx.x; i < m; i += blockDim.x) {
    int e = (u[i] >> 7) & 0xFF;
    if (e != 0 && (e < 97 || e > 158)) local++;
  }
  atomicAdd(&cnt, local);
  __syncthreads();
  if (threadIdx.x == 0) flags[ti] = (cnt >= (m >> 6) + 2) ? 1 : 0;
}

// ---------------- weight pre-conversion: flagged (fp32|bf16) -> bf16 arena ----
// Each weight is CDIM*CDIM elements. Grid: (CDIM*CDIM/8/256, 5).
struct W5 { const void* p[5]; int fi[5]; };

__global__ void conv_w(W5 w, u16* __restrict__ out, const int* __restrict__ flags) {
  int wi = blockIdx.y;
  int f = flags[w.fi[wi]];
  size_t base = (size_t)wi * (CDIM * CDIM);
  int t = blockIdx.x * blockDim.x + threadIdx.x;   // 0 .. CDIM*CDIM/8-1
  size_t e = (size_t)t * 8;
  if (f) {
    const float4* in = (const float4*)w.p[wi];
    float4 a0 = in[t * 2], a1 = in[t * 2 + 1];
    __align__(16) u16 tmp[8];
    tmp[0] = f2bf(san(a0.x)); tmp[1] = f2bf(san(a0.y));
    tmp[2] = f2bf(san(a0.z)); tmp[3] = f2bf(san(a0.w));
    tmp[4] = f2bf(san(a1.x)); tmp[5] = f2bf(san(a1.y));
    tmp[6] = f2bf(san(a1.z)); tmp[7] = f2bf(san(a1.w));
    *(uint4*)&out[base + e] = *(uint4*)tmp;
  } else {
    const uint4* in = (const uint4*)w.p[wi];
    *(uint4*)&out[base + e] = in[t];
  }
}

// ---------------- transpose + zero-pad (dtype-flagged input -> bf16) ----
// in: (NB, C, Lin) ; out: (NB, Lout, C) bf16, rows >= Lin zeroed.
__global__ void transpose_pad(const void* __restrict__ inv, u16* __restrict__ out,
                              int Lin, int Lout, const int* __restrict__ flags, int fidx) {
  __shared__ u16 t[32][33];
  int f = flags[fidx];
  int b = blockIdx.z;
  int l0 = blockIdx.x * 32, c0 = blockIdx.y * 32;
  int x = threadIdx.x, y = threadIdx.y;
  bool valid = (l0 < Lin);   // Lin % 32 == 0: whole tile valid or whole tile pad
  if (valid) {
    for (int r = 0; r < 4; r++) {
      size_t idx = ((size_t)b * CDIM + c0 + y * 4 + r) * Lin + l0 + x;
      t[y * 4 + r][x] = f2bf(ldin(inv, idx, f));
    }
  }
  __syncthreads();
  for (int r = 0; r < 4; r++) {
    int lr = l0 + y * 4 + r;
    out[((size_t)b * Lout + lr) * CDIM + c0 + x] = valid ? t[x][y * 4 + r] : (u16)0;
  }
}

// ---------------- bf16 MFMA GEMM with BN epilogue (m97 structure) ----------
// Out[b, o, l] = (sum_c Wb[o,c] * X[b,c,l]) * sc[o] + sh[o]
// Wb: (1024,1024) row-major bf16 (pre-converted). XT: (NB*Lpad,1024) bf16.
// Out: (NB, 1024, Lpad), bf16 (f32out=0) or fp32 (f32out=1). Lpad % 128 == 0.
// 128x128 tile, BK=32, 4 waves (2x2 of 64x64), linear LDS, global_load_lds x16.
#define BK 32

__global__ __launch_bounds__(256) void gemm_bn(
    const u16* __restrict__ Wb, const u16* __restrict__ XT, void* __restrict__ Out,
    const void* __restrict__ sc, const void* __restrict__ sh, int Lpad,
    const int* __restrict__ flags, int sci, int shi, int f32out) {
  __shared__ __align__(16) u16 As[128 * BK];
  __shared__ __align__(16) u16 Bs[128 * BK];
  const int K = 1024;
  int tid = threadIdx.x;
  int lane = tid & 63, wave = tid >> 6;
  int m0 = blockIdx.y * 128, n0 = blockIdx.x * 128;
  int wm = (wave >> 1) * 64, wn = (wave & 1) * 64;
  // staging geometry: wave handles chunks {2w, 2w+1}; chunk = 16 rows of 32 elems.
  // lane -> (row within chunk, col): row = lane>>2, col = (lane&3)*8.
  // LDS byte addr = chunk*1024 + lane*16  (linear, matches global_load_lds).
  int srow = lane >> 2;
  int scol = (lane & 3) * 8;
  const u16* Ag = Wb + (size_t)(m0 + wave * 32 + srow) * K + scol;
  const u16* Bg = XT + (size_t)(n0 + wave * 32 + srow) * K + scol;
  u16* Asl = &As[(wave * 32 + srow) * BK + scol];
  u16* Bsl = &Bs[(wave * 32 + srow) * BK + scol];
  floatx4 acc[4][4] = {};
  for (int k0 = 0; k0 < K; k0 += BK) {
    __syncthreads();
#pragma unroll
    for (int i = 0; i < 2; i++) {
      gload16(Ag + (size_t)(i * 16) * K + k0, Asl + i * 16 * BK);
      gload16(Bg + (size_t)(i * 16) * K + k0, Bsl + i * 16 * BK);
    }
    __syncthreads();
    int lr = lane & 15, q8 = (lane >> 4) * 8;
    short8 af[4], bfr[4];
#pragma unroll
    for (int f = 0; f < 4; f++) {
      af[f]  = *(const short8*)&As[(wm + f * 16 + lr) * BK + q8];
      bfr[f] = *(const short8*)&Bs[(wn + f * 16 + lr) * BK + q8];
    }
#pragma unroll
    for (int i = 0; i < 4; i++)
#pragma unroll
      for (int j = 0; j < 4; j++)
        acc[i][j] = __builtin_amdgcn_mfma_f32_16x16x32_bf16(af[i], bfr[j], acc[i][j], 0, 0, 0);
  }
  // epilogue: C/D layout col = lane&15, row = (lane>>4)*4 + reg  [m89-verified]
  int sf = flags[sci], hf = flags[shi];
  int colL = lane & 15, rq = (lane >> 4) * 4;
  int b = n0 / Lpad;
  int lb = n0 - b * Lpad;
#pragma unroll
  for (int i = 0; i < 4; i++) {
    int gr0 = m0 + wm + i * 16 + rq;
    float s0 = ldin(sc, gr0, sf),     h0 = ldin(sh, gr0, hf);
    float s1 = ldin(sc, gr0 + 1, sf), h1 = ldin(sh, gr0 + 1, hf);
    float s2 = ldin(sc, gr0 + 2, sf), h2 = ldin(sh, gr0 + 2, hf);
    float s3 = ldin(sc, gr0 + 3, sf), h3 = ldin(sh, gr0 + 3, hf);
#pragma unroll
    for (int j = 0; j < 4; j++) {
      int gc = lb + wn + j * 16 + colL;
      size_t base = ((size_t)b * CDIM + gr0) * Lpad + gc;
      float r0 = acc[i][j][0] * s0 + h0;
      float r1 = acc[i][j][1] * s1 + h1;
      float r2 = acc[i][j][2] * s2 + h2;
      float r3 = acc[i][j][3] * s3 + h3;
      if (f32out) {
        float* O = (float*)Out;
        O[base]                    = r0;
        O[base + (size_t)Lpad]     = r1;
        O[base + 2 * (size_t)Lpad] = r2;
        O[base + 3 * (size_t)Lpad] = r3;
      } else {
        u16* O = (u16*)Out;
        O[base]                    = f2bf(r0);
        O[base + (size_t)Lpad]     = f2bf(r1);
        O[base + 2 * (size_t)Lpad] = f2bf(r2);
        O[base + 3 * (size_t)Lpad] = f2bf(r3);
      }
    }
  }
}

// ---------------- attention P precompute ----------------
// qk: (NB,8,2,64,Lstride) bf16 ws (channel = H*128 + s*64 + d).
// P layout: [lev][bh][g][J][j] fp32, bh = b*8+H, g in [0,G).
template<int BASE>
__global__ void p_compute(const u16* __restrict__ qk, float* __restrict__ P,
                          int Lstride, int n, int G) {
  int lev = blockIdx.y;
  int t = blockIdx.x * blockDim.x + threadIdx.x;
  if (t >= 32 * G) return;
  int g = t % G, bh = t / G;
  int inner = 1;
  for (int i = 0; i < n - 1 - lev; i++) inner *= BASE;
  int ii = g / inner, kk = g - ii * inner;
  const u16* qp = qk + ((size_t)bh * 128) * Lstride;
  const u16* kp = qk + ((size_t)bh * 128 + 64) * Lstride;
  int lpos[BASE];
#pragma unroll
  for (int j = 0; j < BASE; j++) lpos[j] = (ii * BASE + j) * inner + kk;
  float S[BASE][BASE];
#pragma unroll
  for (int J = 0; J < BASE; J++)
#pragma unroll
    for (int j = 0; j < BASE; j++) S[J][j] = 0.f;
  for (int d = 0; d < 64; d++) {
    float qv[BASE], kv[BASE];
#pragma unroll
    for (int j = 0; j < BASE; j++) {
      qv[j] = bf2f(qp[(size_t)d * Lstride + lpos[j]]);
      kv[j] = bf2f(kp[(size_t)d * Lstride + lpos[j]]);
    }
#pragma unroll
    for (int J = 0; J < BASE; J++)
#pragma unroll
      for (int j = 0; j < BASE; j++) S[J][j] += kv[J] * qv[j];
  }
  float* Pg = P + ((size_t)lev * 32 * G + t) * (BASE * BASE);
#pragma unroll
  for (int J = 0; J < BASE; J++) {
    float mx = -1e30f;
#pragma unroll
    for (int j = 0; j < BASE; j++) { S[J][j] *= 0.125f; mx = fmaxf(mx, S[J][j]); }
    float e[BASE]; float sum = 0.f;
#pragma unroll
    for (int j = 0; j < BASE; j++) { e[j] = __expf(S[J][j] - mx); sum += e[j]; }
    float inv = 1.f / sum;
#pragma unroll
    for (int j = 0; j < BASE; j++) Pg[J * BASE + j] = e[j] * inv;
  }
}

// ---------------- apply one attention level to v (may be in-place) -------
template<int BASE>
__global__ void apply_level(const u16* vin, u16* vout,
                            const float* __restrict__ Plev, int inner, int G, int Lstride) {
  size_t t = (size_t)blockIdx.x * blockDim.x + threadIdx.x;
  int g = (int)(t % G);
  size_t rest = t / G;
  int d = (int)(rest & 127);
  int bh = (int)(rest >> 7);
  int ii = g / inner, kk = g - ii * inner;
  size_t rowb = ((size_t)bh * 128 + d) * Lstride;
  const float* Pg = Plev + ((size_t)bh * G + g) * (BASE * BASE);
  float vv[BASE]; int lp[BASE];
#pragma unroll
  for (int j = 0; j < BASE; j++) {
    lp[j] = (ii * BASE + j) * inner + kk;
    vv[j] = bf2f(vin[rowb + lp[j]]);
  }
#pragma unroll
  for (int J = 0; J < BASE; J++) {
    float o = 0.f;
#pragma unroll
    for (int j = 0; j < BASE; j++) o += Pg[J * BASE + j] * vv[j];
    vout[rowb + lp[J]] = f2bf(o);
  }
}

// ---------------- combine: residual + v1 + v2 + BN(dwconv3(v0)) ----------
// y[b,c,l] (stride 4096, bf16) = xres + v1 + v2 + dwconv-BN(v0)
// xres may alias y (stage 3): same-index read-then-write per thread -> safe.
__global__ void combine_pe(const void* xres, const u16* __restrict__ v1,
                           const u16* __restrict__ v2, const u16* __restrict__ v0,
                           const void* __restrict__ wpe, const void* __restrict__ spe,
                           const void* __restrict__ bpe, u16* y,
                           int Lstride, int Lv, const int* __restrict__ flags,
                           int xfi, int wpi, int spi, int bpi) {
  size_t t = (size_t)blockIdx.x * blockDim.x + threadIdx.x;
  int xf = flags[xfi], wf = flags[wpi], sf = flags[spi], bf = flags[bpi];
  int l = (int)(t & 4095);
  size_t ch = t >> 12;            // b*1024 + c
  int c = (int)(ch & 1023);
  size_t rb = ch * Lstride;
  float vm = (l > 0) ? bf2f(v0[rb + l - 1]) : 0.f;
  float vc = bf2f(v0[rb + l]);
  float vp = (l + 1 < Lv) ? bf2f(v0[rb + l + 1]) : 0.f;
  float pe = ldin(wpe, c * 3, wf) * vm + ldin(wpe, c * 3 + 1, wf) * vc +
             ldin(wpe, c * 3 + 2, wf) * vp;
  pe = pe * ldin(spe, c, sf) + ldin(bpe, c, bf);
  float xr = ldin(xres, ch * 4096 + l, xf);
  float r = xr + bf2f(v1[rb + l]) + bf2f(v2[rb + l]) + pe;
  y[ch * 4096 + l] = f2bf(r);
}

static inline int ipow(int b, int e) { int r = 1; for (int i = 0; i < e; i++) r *= b; return r; }

extern "C" void kernel_launch(void* const* d_in, const int* in_sizes, int n_in,
                              void* d_out, int out_size, void* d_ws, size_t ws_size,
                              hipStream_t stream) {
  const int W = 4096;
  const int Ls2 = 4096;                 // stage2 stride == L2
  const int L3 = 6561, Ls3 = 6656;      // stage3: logical / padded stride (52*128)
  const int G2 = 2048, G3 = 2187;       // groups per (b,H)
  const size_t S3e = (size_t)NB * CDIM * Ls3;   // 27,262,976 elements

  // Arena: 3 bf16 slots + P buffer + flags + bf16 weight arena ≈ 194 MB.
  char* p = (char*)d_ws;
  auto alloc = [&](size_t bytes) { char* r = p; p += (bytes + 255) & ~(size_t)255; return r; };
  u16* slotA = (u16*)alloc(S3e * 2);   // xT  -> chain-1 buffer
  u16* slotB = (u16*)alloc(S3e * 2);   // qk  -> chain-2 buffer
  u16* slotC = (u16*)alloc(S3e * 2);   // v0 (kept through each stage)
  float* Pbuf = (float*)alloc((size_t)5038848 * 4);  // max(12*32*G2*4, 8*32*G3*9)
  int* flags = (int*)alloc(64 * 4);
  u16* warena = (u16*)alloc((size_t)5 * CDIM * CDIM * 2);  // 5 bf16 weight copies
  (void)ws_size; (void)n_in; (void)out_size;

  // y2/y3 staging (bf16) lives in the front half of d_out (fp32 buffer,
  // 67 MB; we use the first 33 MB as bf16 scratch until the final GEMM
  // overwrites the whole buffer in fp32).
  u16* ybuf = (u16*)d_out;

  // ---- dtype sniff (writes flags[0..21]; flags[22]=0 = bf16 sentinel) ----
  PtrArgs pa;
  for (int i = 0; i < 22; i++) { pa.p[i] = d_in[i]; pa.n[i] = in_sizes[i]; }
  detect_dtypes<<<23, 256, 0, stream>>>(pa, flags);
  const int BF = 22;  // sentinel flag index (bf16)

  // ---- pre-convert the 5 GEMM weights to bf16 arena (flag-driven) ----
  W5 w5;
  const int widx[5] = {1, 4, 10, 13, 19};
  for (int i = 0; i < 5; i++) { w5.p[i] = d_in[widx[i]]; w5.fi[i] = widx[i]; }
  conv_w<<<dim3(CDIM * CDIM / 8 / 256, 5), 256, 0, stream>>>(w5, warena, flags);
  u16* wb_qk2 = warena;
  u16* wb_v2  = warena + (size_t)1 * CDIM * CDIM;
  u16* wb_qk3 = warena + (size_t)2 * CDIM * CDIM;
  u16* wb_v3  = warena + (size_t)3 * CDIM * CDIM;
  u16* wb_pr  = warena + (size_t)4 * CDIM * CDIM;

  dim3 tb(32, 8);
  const size_t P2lev = (size_t)32 * G2 * 4;
  const size_t P3lev = (size_t)32 * G3 * 9;

  // ================= stage base=2 (n=12, L=4096, no pad) =================
  transpose_pad<<<dim3(Ls2 / 32, CDIM / 32, NB), tb, 0, stream>>>(d_in[0], slotA, W, Ls2, flags, 0);
  gemm_bn<<<dim3(NB * Ls2 / 128, CDIM / 128), 256, 0, stream>>>(
      wb_qk2, slotA, slotB, d_in[2], d_in[3], Ls2, flags, 2, 3, 0);
  gemm_bn<<<dim3(NB * Ls2 / 128, CDIM / 128), 256, 0, stream>>>(
      wb_v2, slotA, slotC, d_in[5], d_in[6], Ls2, flags, 5, 6, 0);
  p_compute<2><<<dim3((32 * G2 + 255) / 256, 12), 256, 0, stream>>>(slotB, Pbuf, Ls2, 12, G2);

  {
    const int apply_blocks = (int)(((size_t)4096 * G2) / 256);  // 32768
    for (int idx = 0; idx < 12; idx++) {           // chain v1: i = 11..0 -> slotA
      int i = 11 - idx;
      const u16* src = (idx == 0) ? slotC : slotA;
      apply_level<2><<<apply_blocks, 256, 0, stream>>>(src, slotA, Pbuf + (size_t)i * P2lev,
                                                       ipow(2, 11 - i), G2, Ls2);
    }
    for (int idx = 0; idx < 12; idx++) {           // chain v2: i = 0..11 -> slotB
      int i = idx;
      const u16* src = (idx == 0) ? slotC : slotB;
      apply_level<2><<<apply_blocks, 256, 0, stream>>>(src, slotB, Pbuf + (size_t)i * P2lev,
                                                       ipow(2, 11 - i), G2, Ls2);
    }
  }
  combine_pe<<<(int)(((size_t)NB * CDIM * 4096) / 256), 256, 0, stream>>>(
      d_in[0], slotA, slotB, slotC, d_in[7], d_in[8], d_in[9], ybuf, Ls2, Ls2,
      flags, 0, 7, 8, 9);

  // ================= stage base=3 (n=8, L=6561, stride 6656) =================
  transpose_pad<<<dim3(Ls3 / 32, CDIM / 32, NB), tb, 0, stream>>>(ybuf, slotA, W, Ls3, flags, BF);
  gemm_bn<<<dim3(NB * Ls3 / 128, CDIM / 128), 256, 0, stream>>>(
      wb_qk3, slotA, slotB, d_in[11], d_in[12], Ls3, flags, 11, 12, 0);
  gemm_bn<<<dim3(NB * Ls3 / 128, CDIM / 128), 256, 0, stream>>>(
      wb_v3, slotA, slotC, d_in[14], d_in[15], Ls3, flags, 14, 15, 0);
  p_compute<3><<<dim3((32 * G3 + 255) / 256, 8), 256, 0, stream>>>(slotB, Pbuf, Ls3, 8, G3);

  {
    const int apply_blocks = (int)(((size_t)4096 * G3) / 256);  // 34992
    for (int idx = 0; idx < 8; idx++) {            // chain v1: i = 7..0 -> slotA
      int i = 7 - idx;
      const u16* src = (idx == 0) ? slotC : slotA;
      apply_level<3><<<apply_blocks, 256, 0, stream>>>(src, slotA, Pbuf + (size_t)i * P3lev,
                                                       ipow(3, 7 - i), G3, Ls3);
    }
    for (int idx = 0; idx < 8; idx++) {            // chain v2: i = 0..7 -> slotB
      int i = idx;
      const u16* src = (idx == 0) ? slotC : slotB;
      apply_level<3><<<apply_blocks, 256, 0, stream>>>(src, slotB, Pbuf + (size_t)i * P3lev,
                                                       ipow(3, 7 - i), G3, Ls3);
    }
  }
  combine_pe<<<(int)(((size_t)NB * CDIM * 4096) / 256), 256, 0, stream>>>(
      ybuf, slotA, slotB, slotC, d_in[16], d_in[17], d_in[18], ybuf, Ls3, L3,
      flags, BF, 16, 17, 18);

  // ================= final projection (fp32 output!) =================
  transpose_pad<<<dim3(Ls2 / 32, CDIM / 32, NB), tb, 0, stream>>>(ybuf, slotA, W, Ls2, flags, BF);
  gemm_bn<<<dim3(NB * Ls2 / 128, CDIM / 128), 256, 0, stream>>>(
      wb_pr, slotA, d_out, d_in[20], d_in[21], Ls2, flags, 20, 21, 1);
}

// Round 2
// 1714.469 us; speedup vs baseline: 1.4122x; 1.1853x over previous
//
#include <hip/hip_runtime.h>

typedef unsigned short u16;
typedef __attribute__((ext_vector_type(8))) short short8;
typedef __attribute__((ext_vector_type(4))) float floatx4;

#define CDIM 1024
#define NB 4

__device__ __forceinline__ float bf2f(u16 u) {
  union { unsigned int i; float f; } v; v.i = ((unsigned int)u) << 16; return v.f;
}
__device__ __forceinline__ u16 f2bf(float f) {
  union { float f; unsigned int i; } v; v.f = f;
  unsigned int r = v.i + 0x7fffu + ((v.i >> 16) & 1u);
  return (u16)(r >> 16);
}
__device__ __forceinline__ float san(float f) {
  return (fabsf(f) <= 3.0e38f) ? f : 0.f;
}
// dtype-flagged input load: flag 1 = fp32, 0 = bf16
__device__ __forceinline__ float ldin(const void* p, size_t i, int f) {
  return f ? san(((const float*)p)[i]) : bf2f(((const u16*)p)[i]);
}

constexpr int cipow(int b, int e) { return e ? b * cipow(b, e - 1) : 1; }

// async global->LDS, 16B per lane. LDS dest must be wave-uniform base + lane*16.
__device__ __forceinline__ void gload16(const u16* g, u16* l) {
  __builtin_amdgcn_global_load_lds(
      (const __attribute__((address_space(1))) void*)g,
      (__attribute__((address_space(3))) void*)l, 16, 0, 0);
}

// ---------------- per-tensor dtype sniffer ----------------
struct PtrArgs { const void* p[22]; int n[22]; };

__global__ void detect_dtypes(PtrArgs a, int* __restrict__ flags) {
  __shared__ int cnt;
  int ti = blockIdx.x;
  if (threadIdx.x == 0) cnt = 0;
  __syncthreads();
  if (ti >= 22) {
    if (threadIdx.x == 0) flags[ti] = 0;
    return;
  }
  const u16* u = (const u16*)a.p[ti];
  int m = a.n[ti]; if (m > 4096) m = 4096;
  int local = 0;
  for (int i = threadIdx.x; i < m; i += blockDim.x) {
    int e = (u[i] >> 7) & 0xFF;
    if (e != 0 && (e < 97 || e > 158)) local++;
  }
  atomicAdd(&cnt, local);
  __syncthreads();
  if (threadIdx.x == 0) flags[ti] = (cnt >= (m >> 6) + 2) ? 1 : 0;
}

// ---------------- weight pre-conversion: flagged (fp32|bf16) -> bf16 arena ----
struct W5 { const void* p[5]; int fi[5]; };

__global__ void conv_w(W5 w, u16* __restrict__ out, const int* __restrict__ flags) {
  int wi = blockIdx.y;
  int f = flags[w.fi[wi]];
  size_t base = (size_t)wi * (CDIM * CDIM);
  int t = blockIdx.x * blockDim.x + threadIdx.x;   // 0 .. CDIM*CDIM/8-1
  size_t e = (size_t)t * 8;
  if (f) {
    const float4* in = (const float4*)w.p[wi];
    float4 a0 = in[t * 2], a1 = in[t * 2 + 1];
    __align__(16) u16 tmp[8];
    tmp[0] = f2bf(san(a0.x)); tmp[1] = f2bf(san(a0.y));
    tmp[2] = f2bf(san(a0.z)); tmp[3] = f2bf(san(a0.w));
    tmp[4] = f2bf(san(a1.x)); tmp[5] = f2bf(san(a1.y));
    tmp[6] = f2bf(san(a1.z)); tmp[7] = f2bf(san(a1.w));
    *(uint4*)&out[base + e] = *(uint4*)tmp;
  } else {
    const uint4* in = (const uint4*)w.p[wi];
    *(uint4*)&out[base + e] = in[t];
  }
}

// ---------------- transpose + zero-pad (dtype-flagged input -> bf16) ----
__global__ void transpose_pad(const void* __restrict__ inv, u16* __restrict__ out,
                              int Lin, int Lout, const int* __restrict__ flags, int fidx) {
  __shared__ u16 t[32][33];
  int f = flags[fidx];
  int b = blockIdx.z;
  int l0 = blockIdx.x * 32, c0 = blockIdx.y * 32;
  int x = threadIdx.x, y = threadIdx.y;
  bool valid = (l0 < Lin);   // Lin % 32 == 0: whole tile valid or whole tile pad
  if (valid) {
    for (int r = 0; r < 4; r++) {
      size_t idx = ((size_t)b * CDIM + c0 + y * 4 + r) * Lin + l0 + x;
      t[y * 4 + r][x] = f2bf(ldin(inv, idx, f));
    }
  }
  __syncthreads();
  for (int r = 0; r < 4; r++) {
    int lr = l0 + y * 4 + r;
    out[((size_t)b * Lout + lr) * CDIM + c0 + x] = valid ? t[x][y * 4 + r] : (u16)0;
  }
}

// ---------------- bf16 MFMA GEMM with BN epilogue (m97 structure) ----------
#define BK 32

__global__ __launch_bounds__(256) void gemm_bn(
    const u16* __restrict__ Wb, const u16* __restrict__ XT, void* __restrict__ Out,
    const void* __restrict__ sc, const void* __restrict__ sh, int Lpad,
    const int* __restrict__ flags, int sci, int shi, int f32out) {
  __shared__ __align__(16) u16 As[128 * BK];
  __shared__ __align__(16) u16 Bs[128 * BK];
  const int K = 1024;
  int tid = threadIdx.x;
  int lane = tid & 63, wave = tid >> 6;
  int m0 = blockIdx.y * 128, n0 = blockIdx.x * 128;
  int wm = (wave >> 1) * 64, wn = (wave & 1) * 64;
  int srow = lane >> 2;
  int scol = (lane & 3) * 8;
  const u16* Ag = Wb + (size_t)(m0 + wave * 32 + srow) * K + scol;
  const u16* Bg = XT + (size_t)(n0 + wave * 32 + srow) * K + scol;
  u16* Asl = &As[(wave * 32 + srow) * BK + scol];
  u16* Bsl = &Bs[(wave * 32 + srow) * BK + scol];
  floatx4 acc[4][4] = {};
  for (int k0 = 0; k0 < K; k0 += BK) {
    __syncthreads();
#pragma unroll
    for (int i = 0; i < 2; i++) {
      gload16(Ag + (size_t)(i * 16) * K + k0, Asl + i * 16 * BK);
      gload16(Bg + (size_t)(i * 16) * K + k0, Bsl + i * 16 * BK);
    }
    __syncthreads();
    int lr = lane & 15, q8 = (lane >> 4) * 8;
    short8 af[4], bfr[4];
#pragma unroll
    for (int f = 0; f < 4; f++) {
      af[f]  = *(const short8*)&As[(wm + f * 16 + lr) * BK + q8];
      bfr[f] = *(const short8*)&Bs[(wn + f * 16 + lr) * BK + q8];
    }
#pragma unroll
    for (int i = 0; i < 4; i++)
#pragma unroll
      for (int j = 0; j < 4; j++)
        acc[i][j] = __builtin_amdgcn_mfma_f32_16x16x32_bf16(af[i], bfr[j], acc[i][j], 0, 0, 0);
  }
  int sf = flags[sci], hf = flags[shi];
  int colL = lane & 15, rq = (lane >> 4) * 4;
  int b = n0 / Lpad;
  int lb = n0 - b * Lpad;
#pragma unroll
  for (int i = 0; i < 4; i++) {
    int gr0 = m0 + wm + i * 16 + rq;
    float s0 = ldin(sc, gr0, sf),     h0 = ldin(sh, gr0, hf);
    float s1 = ldin(sc, gr0 + 1, sf), h1 = ldin(sh, gr0 + 1, hf);
    float s2 = ldin(sc, gr0 + 2, sf), h2 = ldin(sh, gr0 + 2, hf);
    float s3 = ldin(sc, gr0 + 3, sf), h3 = ldin(sh, gr0 + 3, hf);
#pragma unroll
    for (int j = 0; j < 4; j++) {
      int gc = lb + wn + j * 16 + colL;
      size_t base = ((size_t)b * CDIM + gr0) * Lpad + gc;
      float r0 = acc[i][j][0] * s0 + h0;
      float r1 = acc[i][j][1] * s1 + h1;
      float r2 = acc[i][j][2] * s2 + h2;
      float r3 = acc[i][j][3] * s3 + h3;
      if (f32out) {
        float* O = (float*)Out;
        O[base]                    = r0;
        O[base + (size_t)Lpad]     = r1;
        O[base + 2 * (size_t)Lpad] = r2;
        O[base + 3 * (size_t)Lpad] = r3;
      } else {
        u16* O = (u16*)Out;
        O[base]                    = f2bf(r0);
        O[base + (size_t)Lpad]     = f2bf(r1);
        O[base + 2 * (size_t)Lpad] = f2bf(r2);
        O[base + 3 * (size_t)Lpad] = f2bf(r3);
      }
    }
  }
}

// ---------------- attention P precompute ----------------
template<int BASE>
__global__ void p_compute(const u16* __restrict__ qk, float* __restrict__ P,
                          int Lstride, int n, int G) {
  int lev = blockIdx.y;
  int t = blockIdx.x * blockDim.x + threadIdx.x;
  if (t >= 32 * G) return;
  int g = t % G, bh = t / G;
  int inner = 1;
  for (int i = 0; i < n - 1 - lev; i++) inner *= BASE;
  int ii = g / inner, kk = g - ii * inner;
  const u16* qp = qk + ((size_t)bh * 128) * Lstride;
  const u16* kp = qk + ((size_t)bh * 128 + 64) * Lstride;
  int lpos[BASE];
#pragma unroll
  for (int j = 0; j < BASE; j++) lpos[j] = (ii * BASE + j) * inner + kk;
  float S[BASE][BASE];
#pragma unroll
  for (int J = 0; J < BASE; J++)
#pragma unroll
    for (int j = 0; j < BASE; j++) S[J][j] = 0.f;
  for (int d = 0; d < 64; d++) {
    float qv[BASE], kv[BASE];
#pragma unroll
    for (int j = 0; j < BASE; j++) {
      qv[j] = bf2f(qp[(size_t)d * Lstride + lpos[j]]);
      kv[j] = bf2f(kp[(size_t)d * Lstride + lpos[j]]);
    }
#pragma unroll
    for (int J = 0; J < BASE; J++)
#pragma unroll
      for (int j = 0; j < BASE; j++) S[J][j] += kv[J] * qv[j];
  }
  float* Pg = P + ((size_t)lev * 32 * G + t) * (BASE * BASE);
#pragma unroll
  for (int J = 0; J < BASE; J++) {
    float mx = -1e30f;
#pragma unroll
    for (int j = 0; j < BASE; j++) { S[J][j] *= 0.125f; mx = fmaxf(mx, S[J][j]); }
    float e[BASE]; float sum = 0.f;
#pragma unroll
    for (int j = 0; j < BASE; j++) { e[j] = __expf(S[J][j] - mx); sum += e[j]; }
    float inv = 1.f / sum;
#pragma unroll
    for (int j = 0; j < BASE; j++) Pg[J * BASE + j] = e[j] * inv;
  }
}

// ---------------- fused multi-level attention apply ----------------
// Level at digit p (inner = BASE^p) has P-level index lev = N-1-p.
// g for element l = "delete digit p from l" = (l/(B*S_p))*S_p + l%S_p.
// One level applied to the per-thread register group v[E], pairs differ in
// digit Q of the in-group index j. All indices compile-time (rule #20).
template<int BASE, int N, int B0, int Q, int E>
__device__ __forceinline__ void level_apply(float* v, const float* __restrict__ Pst,
                                            int bh, int base_l) {
  constexpr int G = cipow(BASE, N - 1);
  constexpr int p = B0 + Q;
  constexpr int Sp = cipow(BASE, p);
  constexpr int Sb = cipow(BASE, B0);
  constexpr int step = cipow(BASE, Q);
  constexpr size_t PLEV = (size_t)32 * G * BASE * BASE;
  const float* Pl = Pst + (size_t)(N - 1 - p) * PLEV;
#pragma unroll
  for (int m = 0; m < E / BASE; m++) {
    int hi = m / step, lo = m - hi * step;
    int j0 = hi * (step * BASE) + lo;
    int l0 = base_l + j0 * Sb;
    int g = (l0 / (Sp * BASE)) * Sp + (l0 % Sp);
    const float* Pg = Pl + ((size_t)bh * G + g) * (BASE * BASE);
    float in[BASE], out[BASE];
#pragma unroll
    for (int s = 0; s < BASE; s++) in[s] = v[j0 + s * step];
    if constexpr (BASE == 2) {
      float4 pv = *(const float4*)Pg;
      out[0] = pv.x * in[0] + pv.y * in[1];
      out[1] = pv.z * in[0] + pv.w * in[1];
    } else {
#pragma unroll
      for (int J = 0; J < BASE; J++) {
        float o = 0.f;
#pragma unroll
        for (int s = 0; s < BASE; s++) o += Pg[J * BASE + s] * in[s];
        out[J] = o;
      }
    }
#pragma unroll
    for (int J = 0; J < BASE; J++) v[j0 + J * step] = out[J];
  }
}

// Fused pass over NL consecutive digits {B0 .. B0+NL-1}. ASC=1: apply digit
// B0 first (chain v1 order); ASC=0: highest digit first (chain v2 order).
// In-place safe: each thread owns its whole BASE^NL-element group.
template<int BASE, int N, int NL, int B0, int ASC>
__global__ __launch_bounds__(256) void apply_fused(
    const u16* __restrict__ vin, u16* __restrict__ vout,
    const float* __restrict__ Pst, int Lstride) {
  constexpr int E = cipow(BASE, NL);
  constexpr int Sb = cipow(BASE, B0);
  constexpr int L = cipow(BASE, N);
  constexpr int GPR = L / E;                 // element-groups per row
  unsigned int t = blockIdx.x * 256u + threadIdx.x;
  unsigned int r = t % GPR;
  unsigned int row = t / GPR;                // bh*128 + d
  int low = (int)(r % Sb);
  int H = (int)(r / Sb);
  int bh = (int)(row >> 7);
  size_t rowb = (size_t)row * (unsigned int)Lstride;
  int base_l = H * (Sb * E) + low;
  const u16* vi = vin + rowb + base_l;
  u16* vo = vout + rowb + base_l;
  float v[E];
  if constexpr (Sb == 1 && (E % 8) == 0) {
#pragma unroll
    for (int j8 = 0; j8 < E / 8; j8++) {
      short8 x = *(const short8*)(vi + j8 * 8);
#pragma unroll
      for (int k = 0; k < 8; k++) v[j8 * 8 + k] = bf2f((u16)x[k]);
    }
  } else {
#pragma unroll
    for (int j = 0; j < E; j++) v[j] = bf2f(vi[(size_t)j * Sb]);
  }
  if constexpr (ASC) {
    level_apply<BASE, N, B0, 0, E>(v, Pst, bh, base_l);
    if constexpr (NL > 1) level_apply<BASE, N, B0, 1, E>(v, Pst, bh, base_l);
    if constexpr (NL > 2) level_apply<BASE, N, B0, 2, E>(v, Pst, bh, base_l);
    if constexpr (NL > 3) level_apply<BASE, N, B0, 3, E>(v, Pst, bh, base_l);
  } else {
    if constexpr (NL > 3) level_apply<BASE, N, B0, 3, E>(v, Pst, bh, base_l);
    if constexpr (NL > 2) level_apply<BASE, N, B0, 2, E>(v, Pst, bh, base_l);
    if constexpr (NL > 1) level_apply<BASE, N, B0, 1, E>(v, Pst, bh, base_l);
    level_apply<BASE, N, B0, 0, E>(v, Pst, bh, base_l);
  }
  if constexpr (Sb == 1 && (E % 8) == 0) {
#pragma unroll
    for (int j8 = 0; j8 < E / 8; j8++) {
      short8 x;
#pragma unroll
      for (int k = 0; k < 8; k++) x[k] = (short)f2bf(v[j8 * 8 + k]);
      *(short8*)(vo + j8 * 8) = x;
    }
  } else {
#pragma unroll
    for (int j = 0; j < E; j++) vo[(size_t)j * Sb] = f2bf(v[j]);
  }
}

// ---------------- combine: residual + v1 + v2 + BN(dwconv3(v0)) ----------
// Vectorized: 8 elements per thread (short8 / float4 loads, short8 store).
// y[b,c,l] (stride 4096, bf16) = xres + v1 + v2 + dwconv-BN(v0)
// xres may alias y (stage 3): per-thread read-then-write on same range -> safe.
__global__ __launch_bounds__(256) void combine_pe(
    const void* xres, const u16* __restrict__ v1,
    const u16* __restrict__ v2, const u16* __restrict__ v0,
    const void* __restrict__ wpe, const void* __restrict__ spe,
    const void* __restrict__ bpe, u16* y,
    int Lstride, int Lv, const int* __restrict__ flags,
    int xfi, int wpi, int spi, int bpi) {
  unsigned int t = blockIdx.x * 256u + threadIdx.x;
  int xf = flags[xfi], wf = flags[wpi], sf = flags[spi], bf = flags[bpi];
  int l0 = (int)(t & 511u) * 8;
  size_t ch = t >> 9;            // b*1024 + c
  int c = (int)(ch & 1023);
  size_t rb = ch * (unsigned int)Lstride;
  short8 vc8 = *(const short8*)&v0[rb + l0];
  short8 v18 = *(const short8*)&v1[rb + l0];
  short8 v28 = *(const short8*)&v2[rb + l0];
  float vcf[8], vf1[8], vf2[8];
#pragma unroll
  for (int k = 0; k < 8; k++) {
    vcf[k] = bf2f((u16)vc8[k]);
    vf1[k] = bf2f((u16)v18[k]);
    vf2[k] = bf2f((u16)v28[k]);
  }
  float vml = (l0 > 0) ? bf2f(v0[rb + l0 - 1]) : 0.f;
  float vpr = (l0 + 8 < Lv) ? bf2f(v0[rb + l0 + 8]) : 0.f;
  float w0 = ldin(wpe, (size_t)c * 3, wf);
  float w1 = ldin(wpe, (size_t)c * 3 + 1, wf);
  float w2 = ldin(wpe, (size_t)c * 3 + 2, wf);
  float scv = ldin(spe, c, sf), bcv = ldin(bpe, c, bf);
  size_t xb = ch * 4096 + l0;
  float xr[8];
  if (xf) {
    const float* X = (const float*)xres;
    float4 x0 = *(const float4*)&X[xb], x1 = *(const float4*)&X[xb + 4];
    xr[0] = san(x0.x); xr[1] = san(x0.y); xr[2] = san(x0.z); xr[3] = san(x0.w);
    xr[4] = san(x1.x); xr[5] = san(x1.y); xr[6] = san(x1.z); xr[7] = san(x1.w);
  } else {
    short8 x8 = *(const short8*)&((const u16*)xres)[xb];
#pragma unroll
    for (int k = 0; k < 8; k++) xr[k] = bf2f((u16)x8[k]);
  }
  short8 o8;
#pragma unroll
  for (int k = 0; k < 8; k++) {
    float vm = k ? vcf[k - 1] : vml;
    float vp = (k < 7) ? vcf[k + 1] : vpr;
    float pe = (w0 * vm + w1 * vcf[k] + w2 * vp) * scv + bcv;
    o8[k] = (short)f2bf(xr[k] + vf1[k] + vf2[k] + pe);
  }
  *(short8*)&y[xb] = o8;
}

extern "C" void kernel_launch(void* const* d_in, const int* in_sizes, int n_in,
                              void* d_out, int out_size, void* d_ws, size_t ws_size,
                              hipStream_t stream) {
  const int W = 4096;
  const int Ls2 = 4096;                 // stage2 stride == L2
  const int L3 = 6561, Ls3 = 6656;      // stage3: logical / padded stride (52*128)
  const int G2 = 2048, G3 = 2187;       // groups per (b,H)
  const size_t S3e = (size_t)NB * CDIM * Ls3;   // 27,262,976 elements

  // Arena: 3 bf16 slots + P buffer + flags + bf16 weight arena ≈ 194 MB.
  char* p = (char*)d_ws;
  auto alloc = [&](size_t bytes) { char* r = p; p += (bytes + 255) & ~(size_t)255; return r; };
  u16* slotA = (u16*)alloc(S3e * 2);   // xT  -> chain-1 buffer
  u16* slotB = (u16*)alloc(S3e * 2);   // qk  -> chain-2 buffer
  u16* slotC = (u16*)alloc(S3e * 2);   // v0 (kept through each stage)
  float* Pbuf = (float*)alloc((size_t)5038848 * 4);  // max(12*32*G2*4, 8*32*G3*9)
  int* flags = (int*)alloc(64 * 4);
  u16* warena = (u16*)alloc((size_t)5 * CDIM * CDIM * 2);  // 5 bf16 weight copies
  (void)ws_size; (void)n_in; (void)out_size;

  // y2/y3 staging (bf16) lives in the front half of d_out.
  u16* ybuf = (u16*)d_out;

  // ---- dtype sniff (writes flags[0..21]; flags[22]=0 = bf16 sentinel) ----
  PtrArgs pa;
  for (int i = 0; i < 22; i++) { pa.p[i] = d_in[i]; pa.n[i] = in_sizes[i]; }
  detect_dtypes<<<23, 256, 0, stream>>>(pa, flags);
  const int BF = 22;  // sentinel flag index (bf16)

  // ---- pre-convert the 5 GEMM weights to bf16 arena (flag-driven) ----
  W5 w5;
  const int widx[5] = {1, 4, 10, 13, 19};
  for (int i = 0; i < 5; i++) { w5.p[i] = d_in[widx[i]]; w5.fi[i] = widx[i]; }
  conv_w<<<dim3(CDIM * CDIM / 8 / 256, 5), 256, 0, stream>>>(w5, warena, flags);
  u16* wb_qk2 = warena;
  u16* wb_v2  = warena + (size_t)1 * CDIM * CDIM;
  u16* wb_qk3 = warena + (size_t)2 * CDIM * CDIM;
  u16* wb_v3  = warena + (size_t)3 * CDIM * CDIM;
  u16* wb_pr  = warena + (size_t)4 * CDIM * CDIM;

  dim3 tb(32, 8);
  const int cpe_blocks = (int)(((size_t)NB * CDIM * 4096) / (8 * 256));  // 8192

  // ================= stage base=2 (n=12, L=4096, no pad) =================
  transpose_pad<<<dim3(Ls2 / 32, CDIM / 32, NB), tb, 0, stream>>>(d_in[0], slotA, W, Ls2, flags, 0);
  gemm_bn<<<dim3(NB * Ls2 / 128, CDIM / 128), 256, 0, stream>>>(
      wb_qk2, slotA, slotB, d_in[2], d_in[3], Ls2, flags, 2, 3, 0);
  gemm_bn<<<dim3(NB * Ls2 / 128, CDIM / 128), 256, 0, stream>>>(
      wb_v2, slotA, slotC, d_in[5], d_in[6], Ls2, flags, 5, 6, 0);
  p_compute<2><<<dim3((32 * G2 + 255) / 256, 12), 256, 0, stream>>>(slotB, Pbuf, Ls2, 12, G2);

  // fused apply: rows=4096, groups/row = 4096/16 = 256 -> 4096 blocks
  // v1 chain: digits ascending p=0..11  (original i = 11..0)
  apply_fused<2, 12, 4, 0, 1><<<4096, 256, 0, stream>>>(slotC, slotA, Pbuf, Ls2);
  apply_fused<2, 12, 4, 4, 1><<<4096, 256, 0, stream>>>(slotA, slotA, Pbuf, Ls2);
  apply_fused<2, 12, 4, 8, 1><<<4096, 256, 0, stream>>>(slotA, slotA, Pbuf, Ls2);
  // v2 chain: digits descending p=11..0 (original i = 0..11)
  apply_fused<2, 12, 4, 8, 0><<<4096, 256, 0, stream>>>(slotC, slotB, Pbuf, Ls2);
  apply_fused<2, 12, 4, 4, 0><<<4096, 256, 0, stream>>>(slotB, slotB, Pbuf, Ls2);
  apply_fused<2, 12, 4, 0, 0><<<4096, 256, 0, stream>>>(slotB, slotB, Pbuf, Ls2);

  combine_pe<<<cpe_blocks, 256, 0, stream>>>(
      d_in[0], slotA, slotB, slotC, d_in[7], d_in[8], d_in[9], ybuf, Ls2, Ls2,
      flags, 0, 7, 8, 9);

  // ================= stage base=3 (n=8, L=6561, stride 6656) =================
  transpose_pad<<<dim3(Ls3 / 32, CDIM / 32, NB), tb, 0, stream>>>(ybuf, slotA, W, Ls3, flags, BF);
  gemm_bn<<<dim3(NB * Ls3 / 128, CDIM / 128), 256, 0, stream>>>(
      wb_qk3, slotA, slotB, d_in[11], d_in[12], Ls3, flags, 11, 12, 0);
  gemm_bn<<<dim3(NB * Ls3 / 128, CDIM / 128), 256, 0, stream>>>(
      wb_v3, slotA, slotC, d_in[14], d_in[15], Ls3, flags, 14, 15, 0);
  p_compute<3><<<dim3((32 * G3 + 255) / 256, 8), 256, 0, stream>>>(slotB, Pbuf, Ls3, 8, G3);

  // rows=4096; NL=3: groups/row = 3^5 = 243 -> 3888 blocks; NL=2: 729 -> 11664
  // v1 chain: digits ascending p=0..7  (original i = 7..0)
  apply_fused<3, 8, 3, 0, 1><<<3888, 256, 0, stream>>>(slotC, slotA, Pbuf, Ls3);
  apply_fused<3, 8, 3, 3, 1><<<3888, 256, 0, stream>>>(slotA, slotA, Pbuf, Ls3);
  apply_fused<3, 8, 2, 6, 1><<<11664, 256, 0, stream>>>(slotA, slotA, Pbuf, Ls3);
  // v2 chain: digits descending p=7..0 (original i = 0..7)
  apply_fused<3, 8, 2, 6, 0><<<11664, 256, 0, stream>>>(slotC, slotB, Pbuf, Ls3);
  apply_fused<3, 8, 3, 3, 0><<<3888, 256, 0, stream>>>(slotB, slotB, Pbuf, Ls3);
  apply_fused<3, 8, 3, 0, 0><<<3888, 256, 0, stream>>>(slotB, slotB, Pbuf, Ls3);

  combine_pe<<<cpe_blocks, 256, 0, stream>>>(
      ybuf, slotA, slotB, slotC, d_in[16], d_in[17], d_in[18], ybuf, Ls3, L3,
      flags, BF, 16, 17, 18);

  // ================= final projection (fp32 output!) =================
  transpose_pad<<<dim3(Ls2 / 32, CDIM / 32, NB), tb, 0, stream>>>(ybuf, slotA, W, Ls2, flags, BF);
  gemm_bn<<<dim3(NB * Ls2 / 128, CDIM / 128), 256, 0, stream>>>(
      wb_pr, slotA, d_out, d_in[20], d_in[21], Ls2, flags, 20, 21, 1);
}

// Round 3
// 1284.981 us; speedup vs baseline: 1.8842x; 1.3342x over previous
//
#include <hip/hip_runtime.h>

typedef unsigned short u16;
typedef __attribute__((ext_vector_type(8))) short short8;
typedef __attribute__((ext_vector_type(4))) float floatx4;

#define CDIM 1024
#define NB 4

__device__ __forceinline__ float bf2f(u16 u) {
  union { unsigned int i; float f; } v; v.i = ((unsigned int)u) << 16; return v.f;
}
__device__ __forceinline__ u16 f2bf(float f) {
  union { float f; unsigned int i; } v; v.f = f;
  unsigned int r = v.i + 0x7fffu + ((v.i >> 16) & 1u);
  return (u16)(r >> 16);
}
__device__ __forceinline__ float san(float f) {
  return (fabsf(f) <= 3.0e38f) ? f : 0.f;
}
// dtype-flagged input load: flag 1 = fp32, 0 = bf16
__device__ __forceinline__ float ldin(const void* p, size_t i, int f) {
  return f ? san(((const float*)p)[i]) : bf2f(((const u16*)p)[i]);
}

constexpr int cipow(int b, int e) { return e ? b * cipow(b, e - 1) : 1; }

// async global->LDS, 16B per lane. LDS dest must be wave-uniform base + lane*16.
__device__ __forceinline__ void gload16(const u16* g, u16* l) {
  __builtin_amdgcn_global_load_lds(
      (const __attribute__((address_space(1))) void*)g,
      (__attribute__((address_space(3))) void*)l, 16, 0, 0);
}

// ---------------- per-tensor dtype sniffer ----------------
struct PtrArgs { const void* p[22]; int n[22]; };

__global__ void detect_dtypes(PtrArgs a, int* __restrict__ flags) {
  __shared__ int cnt;
  int ti = blockIdx.x;
  if (threadIdx.x == 0) cnt = 0;
  __syncthreads();
  if (ti >= 22) {
    if (threadIdx.x == 0) flags[ti] = 0;
    return;
  }
  const u16* u = (const u16*)a.p[ti];
  int m = a.n[ti]; if (m > 4096) m = 4096;
  int local = 0;
  for (int i = threadIdx.x; i < m; i += blockDim.x) {
    int e = (u[i] >> 7) & 0xFF;
    if (e != 0 && (e < 97 || e > 158)) local++;
  }
  atomicAdd(&cnt, local);
  __syncthreads();
  if (threadIdx.x == 0) flags[ti] = (cnt >= (m >> 6) + 2) ? 1 : 0;
}

// ---------------- weight pre-conversion: flagged (fp32|bf16) -> bf16 arena ----
struct W5 { const void* p[5]; int fi[5]; };

__global__ void conv_w(W5 w, u16* __restrict__ out, const int* __restrict__ flags) {
  int wi = blockIdx.y;
  int f = flags[w.fi[wi]];
  size_t base = (size_t)wi * (CDIM * CDIM);
  int t = blockIdx.x * blockDim.x + threadIdx.x;   // 0 .. CDIM*CDIM/8-1
  size_t e = (size_t)t * 8;
  if (f) {
    const float4* in = (const float4*)w.p[wi];
    float4 a0 = in[t * 2], a1 = in[t * 2 + 1];
    __align__(16) u16 tmp[8];
    tmp[0] = f2bf(san(a0.x)); tmp[1] = f2bf(san(a0.y));
    tmp[2] = f2bf(san(a0.z)); tmp[3] = f2bf(san(a0.w));
    tmp[4] = f2bf(san(a1.x)); tmp[5] = f2bf(san(a1.y));
    tmp[6] = f2bf(san(a1.z)); tmp[7] = f2bf(san(a1.w));
    *(uint4*)&out[base + e] = *(uint4*)tmp;
  } else {
    const uint4* in = (const uint4*)w.p[wi];
    *(uint4*)&out[base + e] = in[t];
  }
}

// ---------------- transpose + zero-pad (dtype-flagged input -> bf16) ----
__global__ void transpose_pad(const void* __restrict__ inv, u16* __restrict__ out,
                              int Lin, int Lout, const int* __restrict__ flags, int fidx) {
  __shared__ u16 t[32][33];
  int f = flags[fidx];
  int b = blockIdx.z;
  int l0 = blockIdx.x * 32, c0 = blockIdx.y * 32;
  int x = threadIdx.x, y = threadIdx.y;
  bool valid = (l0 < Lin);   // Lin % 32 == 0: whole tile valid or whole tile pad
  if (valid) {
    for (int r = 0; r < 4; r++) {
      size_t idx = ((size_t)b * CDIM + c0 + y * 4 + r) * Lin + l0 + x;
      t[y * 4 + r][x] = f2bf(ldin(inv, idx, f));
    }
  }
  __syncthreads();
  for (int r = 0; r < 4; r++) {
    int lr = l0 + y * 4 + r;
    out[((size_t)b * Lout + lr) * CDIM + c0 + x] = valid ? t[x][y * 4 + r] : (u16)0;
  }
}

// ---------------- bf16 MFMA GEMM with BN epilogue (m97 structure) ----------
#define BK 32

__global__ __launch_bounds__(256) void gemm_bn(
    const u16* __restrict__ Wb, const u16* __restrict__ XT, void* __restrict__ Out,
    const void* __restrict__ sc, const void* __restrict__ sh, int Lpad,
    const int* __restrict__ flags, int sci, int shi, int f32out) {
  __shared__ __align__(16) u16 As[128 * BK];
  __shared__ __align__(16) u16 Bs[128 * BK];
  const int K = 1024;
  int tid = threadIdx.x;
  int lane = tid & 63, wave = tid >> 6;
  int m0 = blockIdx.y * 128, n0 = blockIdx.x * 128;
  int wm = (wave >> 1) * 64, wn = (wave & 1) * 64;
  int srow = lane >> 2;
  int scol = (lane & 3) * 8;
  const u16* Ag = Wb + (size_t)(m0 + wave * 32 + srow) * K + scol;
  const u16* Bg = XT + (size_t)(n0 + wave * 32 + srow) * K + scol;
  u16* Asl = &As[(wave * 32 + srow) * BK + scol];
  u16* Bsl = &Bs[(wave * 32 + srow) * BK + scol];
  floatx4 acc[4][4] = {};
  for (int k0 = 0; k0 < K; k0 += BK) {
    __syncthreads();
#pragma unroll
    for (int i = 0; i < 2; i++) {
      gload16(Ag + (size_t)(i * 16) * K + k0, Asl + i * 16 * BK);
      gload16(Bg + (size_t)(i * 16) * K + k0, Bsl + i * 16 * BK);
    }
    __syncthreads();
    int lr = lane & 15, q8 = (lane >> 4) * 8;
    short8 af[4], bfr[4];
#pragma unroll
    for (int f = 0; f < 4; f++) {
      af[f]  = *(const short8*)&As[(wm + f * 16 + lr) * BK + q8];
      bfr[f] = *(const short8*)&Bs[(wn + f * 16 + lr) * BK + q8];
    }
#pragma unroll
    for (int i = 0; i < 4; i++)
#pragma unroll
      for (int j = 0; j < 4; j++)
        acc[i][j] = __builtin_amdgcn_mfma_f32_16x16x32_bf16(af[i], bfr[j], acc[i][j], 0, 0, 0);
  }
  int sf = flags[sci], hf = flags[shi];
  int colL = lane & 15, rq = (lane >> 4) * 4;
  int b = n0 / Lpad;
  int lb = n0 - b * Lpad;
#pragma unroll
  for (int i = 0; i < 4; i++) {
    int gr0 = m0 + wm + i * 16 + rq;
    float s0 = ldin(sc, gr0, sf),     h0 = ldin(sh, gr0, hf);
    float s1 = ldin(sc, gr0 + 1, sf), h1 = ldin(sh, gr0 + 1, hf);
    float s2 = ldin(sc, gr0 + 2, sf), h2 = ldin(sh, gr0 + 2, hf);
    float s3 = ldin(sc, gr0 + 3, sf), h3 = ldin(sh, gr0 + 3, hf);
#pragma unroll
    for (int j = 0; j < 4; j++) {
      int gc = lb + wn + j * 16 + colL;
      size_t base = ((size_t)b * CDIM + gr0) * Lpad + gc;
      float r0 = acc[i][j][0] * s0 + h0;
      float r1 = acc[i][j][1] * s1 + h1;
      float r2 = acc[i][j][2] * s2 + h2;
      float r3 = acc[i][j][3] * s3 + h3;
      if (f32out) {
        float* O = (float*)Out;
        O[base]                    = r0;
        O[base + (size_t)Lpad]     = r1;
        O[base + 2 * (size_t)Lpad] = r2;
        O[base + 3 * (size_t)Lpad] = r3;
      } else {
        u16* O = (u16*)Out;
        O[base]                    = f2bf(r0);
        O[base + (size_t)Lpad]     = f2bf(r1);
        O[base + 2 * (size_t)Lpad] = f2bf(r2);
        O[base + 3 * (size_t)Lpad] = f2bf(r3);
      }
    }
  }
}

// ---------------- attention P precompute ----------------
// P slot stride padded to 16B multiple: base2 -> 4 floats, base3 -> 12 floats.
template<int BASE>
__global__ void p_compute(const u16* __restrict__ qk, float* __restrict__ P,
                          int Lstride, int n, int G) {
  constexpr int PSTR = (BASE == 2) ? 4 : 12;
  int lev = blockIdx.y;
  int t = blockIdx.x * blockDim.x + threadIdx.x;
  if (t >= 32 * G) return;
  int g = t % G, bh = t / G;
  int inner = 1;
  for (int i = 0; i < n - 1 - lev; i++) inner *= BASE;
  int ii = g / inner, kk = g - ii * inner;
  const u16* qp = qk + ((size_t)bh * 128) * Lstride;
  const u16* kp = qk + ((size_t)bh * 128 + 64) * Lstride;
  int lpos[BASE];
#pragma unroll
  for (int j = 0; j < BASE; j++) lpos[j] = (ii * BASE + j) * inner + kk;
  float S[BASE][BASE];
#pragma unroll
  for (int J = 0; J < BASE; J++)
#pragma unroll
    for (int j = 0; j < BASE; j++) S[J][j] = 0.f;
  for (int d = 0; d < 64; d++) {
    float qv[BASE], kv[BASE];
#pragma unroll
    for (int j = 0; j < BASE; j++) {
      qv[j] = bf2f(qp[(size_t)d * Lstride + lpos[j]]);
      kv[j] = bf2f(kp[(size_t)d * Lstride + lpos[j]]);
    }
#pragma unroll
    for (int J = 0; J < BASE; J++)
#pragma unroll
      for (int j = 0; j < BASE; j++) S[J][j] += kv[J] * qv[j];
  }
  float* Pg = P + ((size_t)lev * 32 * G + t) * PSTR;
#pragma unroll
  for (int J = 0; J < BASE; J++) {
    float mx = -1e30f;
#pragma unroll
    for (int j = 0; j < BASE; j++) { S[J][j] *= 0.125f; mx = fmaxf(mx, S[J][j]); }
    float e[BASE]; float sum = 0.f;
#pragma unroll
    for (int j = 0; j < BASE; j++) { e[j] = __expf(S[J][j] - mx); sum += e[j]; }
    float inv = 1.f / sum;
#pragma unroll
    for (int j = 0; j < BASE; j++) Pg[J * BASE + j] = e[j] * inv;
  }
}

// ---------------- in-LDS level apply ----------------
// Level digit p: groups g in [0, L/B); element l = ii*(B*inner)+J*inner+kk,
// g = ii*inner+kk. Thread-disjoint groups -> in-place W update, barrier between
// levels. P rows are float4-aligned (PSTR).
template<int B, int N, int p>
__device__ __forceinline__ void lds_level(float* W, const float* __restrict__ Pl) {
  constexpr int L = cipow(B, N);
  constexpr int inner = cipow(B, p);
  constexpr int G = L / B;
  constexpr int PSTR = (B == 2) ? 4 : 12;
  for (int g = threadIdx.x; g < G; g += 256) {
    int ii = g / inner, kk = g - ii * inner;
    int base = ii * (B * inner) + kk;
    if constexpr (B == 2) {
      float4 pv = *(const float4*)(Pl + (size_t)g * PSTR);
      float i0 = W[base], i1 = W[base + inner];
      W[base]         = pv.x * i0 + pv.y * i1;
      W[base + inner] = pv.z * i0 + pv.w * i1;
    } else {
      const float4* Pg = (const float4*)(Pl + (size_t)g * PSTR);
      float4 a = Pg[0], b4 = Pg[1], c4 = Pg[2];
      float i0 = W[base], i1 = W[base + inner], i2 = W[base + 2 * inner];
      W[base]             = a.x * i0 + a.y  * i1 + a.z  * i2;
      W[base + inner]     = a.w * i0 + b4.x * i1 + b4.y * i2;
      W[base + 2 * inner] = b4.z * i0 + b4.w * i1 + c4.x * i2;
    }
  }
}

template<int B, int N, int p, bool up>
__device__ __forceinline__ void chain_rec(float* W, const float* __restrict__ Pb, int bh) {
  constexpr int G = cipow(B, N) / B;
  constexpr int PSTR = (B == 2) ? 4 : 12;
  constexpr size_t PLEV = (size_t)32 * G * PSTR;
  __syncthreads();
  lds_level<B, N, p>(W, Pb + (size_t)(N - 1 - p) * PLEV + (size_t)bh * G * PSTR);
  if constexpr (up) {
    if constexpr (p + 1 < N) chain_rec<B, N, p + 1, true>(W, Pb, bh);
  } else {
    if constexpr (p > 0) chain_rec<B, N, p - 1, false>(W, Pb, bh);
  }
}

// copy bf16 LDS row -> fp32 LDS work buffer (vectorized + tail)
template<int L>
__device__ __forceinline__ void initW(float* W, const u16* V0) {
  constexpr int L8 = L / 8;
  for (int i = threadIdx.x; i < L8; i += 256) {
    short8 x = *(const short8*)&V0[i * 8];
    float4 f0, f1;
    f0.x = bf2f((u16)x[0]); f0.y = bf2f((u16)x[1]);
    f0.z = bf2f((u16)x[2]); f0.w = bf2f((u16)x[3]);
    f1.x = bf2f((u16)x[4]); f1.y = bf2f((u16)x[5]);
    f1.z = bf2f((u16)x[6]); f1.w = bf2f((u16)x[7]);
    *(float4*)&W[i * 8] = f0;
    *(float4*)&W[i * 8 + 4] = f1;
  }
  for (int i = L8 * 8 + threadIdx.x; i < L; i += 256) W[i] = bf2f(V0[i]);
}

// ---------------- fused attention chains + combine ----------------
// One block per row (b*1024 + c). Full row in LDS; both level-chains computed
// in-place in fp32 LDS; epilogue = xres + v1 + v2 + BN(dwconv3(v0)) -> y.
// xres may alias y (stage 3): each thread reads its own 16 elems then writes.
template<int BASE, int N, int LSTR>
__global__ __launch_bounds__(256) void fused_chains(
    const u16* __restrict__ v0, const void* __restrict__ xres,
    const void* __restrict__ wpe, const void* __restrict__ spe,
    const void* __restrict__ bpe, u16* __restrict__ y,
    const float* __restrict__ Pb, const int* __restrict__ flags,
    int xfi, int wpi, int spi, int bpi) {
  constexpr int L = cipow(BASE, N);
  __shared__ __align__(16) u16 V0[LSTR];
  __shared__ __align__(16) float W[L];
  int row = blockIdx.x;              // b*1024 + c, c = H*128 + d
  int bh = row >> 7;
  int tid = threadIdx.x;
  const u16* vrow = v0 + (size_t)row * LSTR;
  for (int i = tid; i < LSTR / 8; i += 256)
    *(short8*)&V0[i * 8] = *(const short8*)&vrow[i * 8];
  __syncthreads();
  initW<L>(W, V0);
  // chain v1: digits ascending p = 0..N-1 (original i = N-1..0)
  chain_rec<BASE, N, 0, true>(W, Pb, bh);
  __syncthreads();
  int l0 = tid * 16;                 // covers [0,4096) = output width
  float acc[16];
#pragma unroll
  for (int k = 0; k < 16; k += 4) {
    float4 w4 = *(const float4*)&W[l0 + k];
    acc[k] = w4.x; acc[k + 1] = w4.y; acc[k + 2] = w4.z; acc[k + 3] = w4.w;
  }
  __syncthreads();
  initW<L>(W, V0);
  // chain v2: digits descending p = N-1..0 (original i = 0..N-1)
  chain_rec<BASE, N, N - 1, false>(W, Pb, bh);
  __syncthreads();
#pragma unroll
  for (int k = 0; k < 16; k += 4) {
    float4 w4 = *(const float4*)&W[l0 + k];
    acc[k] += w4.x; acc[k + 1] += w4.y; acc[k + 2] += w4.z; acc[k + 3] += w4.w;
  }
  // epilogue: dwconv-BN(v0) + residual
  int c = row & (CDIM - 1);
  int xf = flags[xfi], wf = flags[wpi], sf = flags[spi], bfg = flags[bpi];
  float w0 = ldin(wpe, (size_t)c * 3, wf);
  float w1 = ldin(wpe, (size_t)c * 3 + 1, wf);
  float w2 = ldin(wpe, (size_t)c * 3 + 2, wf);
  float scv = ldin(spe, c, sf), bcv = ldin(bpe, c, bfg);
  float vcf[16];
#pragma unroll
  for (int k = 0; k < 16; k++) vcf[k] = bf2f(V0[l0 + k]);
  float vml = (l0 > 0) ? bf2f(V0[l0 - 1]) : 0.f;
  float vpr = (l0 + 16 < L) ? bf2f(V0[l0 + 16]) : 0.f;
  size_t xb = (size_t)row * 4096 + l0;
  float xr[16];
  if (xf) {
    const float* X = (const float*)xres;
#pragma unroll
    for (int k = 0; k < 16; k += 4) {
      float4 x4 = *(const float4*)&X[xb + k];
      xr[k] = san(x4.x); xr[k + 1] = san(x4.y);
      xr[k + 2] = san(x4.z); xr[k + 3] = san(x4.w);
    }
  } else {
    const u16* X = (const u16*)xres;
#pragma unroll
    for (int k8 = 0; k8 < 2; k8++) {
      short8 x8 = *(const short8*)&X[xb + k8 * 8];
#pragma unroll
      for (int k = 0; k < 8; k++) xr[k8 * 8 + k] = bf2f((u16)x8[k]);
    }
  }
  short8 o[2];
#pragma unroll
  for (int k = 0; k < 16; k++) {
    float vm = k ? vcf[k - 1] : vml;
    float vp = (k < 15) ? vcf[k + 1] : vpr;
    float pe = (w0 * vm + w1 * vcf[k] + w2 * vp) * scv + bcv;
    o[k >> 3][k & 7] = (short)f2bf(xr[k] + acc[k] + pe);
  }
  *(short8*)&y[xb] = o[0];
  *(short8*)&y[xb + 8] = o[1];
}

extern "C" void kernel_launch(void* const* d_in, const int* in_sizes, int n_in,
                              void* d_out, int out_size, void* d_ws, size_t ws_size,
                              hipStream_t stream) {
  const int W = 4096;
  const int Ls2 = 4096;                 // stage2 stride == L2
  const int Ls3 = 6656;                 // stage3: stride (52*128), L3 = 6561
  const int G2 = 2048, G3 = 2187;       // groups per (b,H)
  const size_t S3e = (size_t)NB * CDIM * Ls3;   // 27,262,976 elements

  // Arena: 3 bf16 slots + flags + bf16 weight arena ≈ 174 MB.
  // Pbuf aliases slotA: xT is dead once both GEMMs have run (sequential
  // stream), and P is dead before the next transpose writes slotA again.
  char* p = (char*)d_ws;
  auto alloc = [&](size_t bytes) { char* r = p; p += (bytes + 255) & ~(size_t)255; return r; };
  u16* slotA = (u16*)alloc(S3e * 2);   // xT ; later aliased by Pbuf
  u16* slotB = (u16*)alloc(S3e * 2);   // qk
  u16* slotC = (u16*)alloc(S3e * 2);   // v0
  int* flags = (int*)alloc(64 * 4);
  u16* warena = (u16*)alloc((size_t)5 * CDIM * CDIM * 2);  // 5 bf16 weight copies
  float* Pbuf = (float*)slotA;         // max P: base3 = 8*32*2187*12*4 B = 33.6 MB
  (void)ws_size; (void)n_in; (void)out_size;

  // y2/y3 staging (bf16) lives in the front half of d_out.
  u16* ybuf = (u16*)d_out;

  // ---- dtype sniff (writes flags[0..21]; flags[22]=0 = bf16 sentinel) ----
  PtrArgs pa;
  for (int i = 0; i < 22; i++) { pa.p[i] = d_in[i]; pa.n[i] = in_sizes[i]; }
  detect_dtypes<<<23, 256, 0, stream>>>(pa, flags);
  const int BF = 22;  // sentinel flag index (bf16)

  // ---- pre-convert the 5 GEMM weights to bf16 arena (flag-driven) ----
  W5 w5;
  const int widx[5] = {1, 4, 10, 13, 19};
  for (int i = 0; i < 5; i++) { w5.p[i] = d_in[widx[i]]; w5.fi[i] = widx[i]; }
  conv_w<<<dim3(CDIM * CDIM / 8 / 256, 5), 256, 0, stream>>>(w5, warena, flags);
  u16* wb_qk2 = warena;
  u16* wb_v2  = warena + (size_t)1 * CDIM * CDIM;
  u16* wb_qk3 = warena + (size_t)2 * CDIM * CDIM;
  u16* wb_v3  = warena + (size_t)3 * CDIM * CDIM;
  u16* wb_pr  = warena + (size_t)4 * CDIM * CDIM;

  dim3 tb(32, 8);

  // ================= stage base=2 (n=12, L=4096, no pad) =================
  transpose_pad<<<dim3(Ls2 / 32, CDIM / 32, NB), tb, 0, stream>>>(d_in[0], slotA, W, Ls2, flags, 0);
  gemm_bn<<<dim3(NB * Ls2 / 128, CDIM / 128), 256, 0, stream>>>(
      wb_qk2, slotA, slotB, d_in[2], d_in[3], Ls2, flags, 2, 3, 0);
  gemm_bn<<<dim3(NB * Ls2 / 128, CDIM / 128), 256, 0, stream>>>(
      wb_v2, slotA, slotC, d_in[5], d_in[6], Ls2, flags, 5, 6, 0);
  p_compute<2><<<dim3((32 * G2 + 255) / 256, 12), 256, 0, stream>>>(slotB, Pbuf, Ls2, 12, G2);
  fused_chains<2, 12, 4096><<<NB * CDIM, 256, 0, stream>>>(
      slotC, d_in[0], d_in[7], d_in[8], d_in[9], ybuf, Pbuf, flags, 0, 7, 8, 9);

  // ================= stage base=3 (n=8, L=6561, stride 6656) =================
  transpose_pad<<<dim3(Ls3 / 32, CDIM / 32, NB), tb, 0, stream>>>(ybuf, slotA, W, Ls3, flags, BF);
  gemm_bn<<<dim3(NB * Ls3 / 128, CDIM / 128), 256, 0, stream>>>(
      wb_qk3, slotA, slotB, d_in[11], d_in[12], Ls3, flags, 11, 12, 0);
  gemm_bn<<<dim3(NB * Ls3 / 128, CDIM / 128), 256, 0, stream>>>(
      wb_v3, slotA, slotC, d_in[14], d_in[15], Ls3, flags, 14, 15, 0);
  p_compute<3><<<dim3((32 * G3 + 255) / 256, 8), 256, 0, stream>>>(slotB, Pbuf, Ls3, 8, G3);
  fused_chains<3, 8, 6656><<<NB * CDIM, 256, 0, stream>>>(
      slotC, ybuf, d_in[16], d_in[17], d_in[18], ybuf, Pbuf, flags, BF, 16, 17, 18);

  // ================= final projection (fp32 output!) =================
  transpose_pad<<<dim3(Ls2 / 32, CDIM / 32, NB), tb, 0, stream>>>(ybuf, slotA, W, Ls2, flags, BF);
  gemm_bn<<<dim3(NB * Ls2 / 128, CDIM / 128), 256, 0, stream>>>(
      wb_pr, slotA, d_out, d_in[20], d_in[21], Ls2, flags, 20, 21, 1);
}

// Round 4
// 1277.913 us; speedup vs baseline: 1.8946x; 1.0055x over previous
//
#include <hip/hip_runtime.h>

typedef unsigned short u16;
typedef __attribute__((ext_vector_type(8))) short short8;
typedef __attribute__((ext_vector_type(4))) short short4v;
typedef __attribute__((ext_vector_type(4))) float floatx4;

#define CDIM 1024
#define NB 4

__device__ __forceinline__ float bf2f(u16 u) {
  union { unsigned int i; float f; } v; v.i = ((unsigned int)u) << 16; return v.f;
}
__device__ __forceinline__ u16 f2bf(float f) {
  union { float f; unsigned int i; } v; v.f = f;
  unsigned int r = v.i + 0x7fffu + ((v.i >> 16) & 1u);
  return (u16)(r >> 16);
}
__device__ __forceinline__ float san(float f) {
  return (fabsf(f) <= 3.0e38f) ? f : 0.f;
}
// dtype-flagged input load: flag 1 = fp32, 0 = bf16
__device__ __forceinline__ float ldin(const void* p, size_t i, int f) {
  return f ? san(((const float*)p)[i]) : bf2f(((const u16*)p)[i]);
}

constexpr int cipow(int b, int e) { return e ? b * cipow(b, e - 1) : 1; }

// async global->LDS, 16B per lane. LDS dest must be wave-uniform base + lane*16.
__device__ __forceinline__ void gload16(const u16* g, u16* l) {
  __builtin_amdgcn_global_load_lds(
      (const __attribute__((address_space(1))) void*)g,
      (__attribute__((address_space(3))) void*)l, 16, 0, 0);
}

// ---------------- per-tensor dtype sniffer ----------------
struct PtrArgs { const void* p[22]; int n[22]; };

__global__ void detect_dtypes(PtrArgs a, int* __restrict__ flags) {
  __shared__ int cnt;
  int ti = blockIdx.x;
  if (threadIdx.x == 0) cnt = 0;
  __syncthreads();
  if (ti >= 22) {
    if (threadIdx.x == 0) flags[ti] = 0;
    return;
  }
  const u16* u = (const u16*)a.p[ti];
  int m = a.n[ti]; if (m > 4096) m = 4096;
  int local = 0;
  for (int i = threadIdx.x; i < m; i += blockDim.x) {
    int e = (u[i] >> 7) & 0xFF;
    if (e != 0 && (e < 97 || e > 158)) local++;
  }
  atomicAdd(&cnt, local);
  __syncthreads();
  if (threadIdx.x == 0) flags[ti] = (cnt >= (m >> 6) + 2) ? 1 : 0;
}

// ---------------- weight pre-conversion: flagged (fp32|bf16) -> bf16 arena ----
struct W5 { const void* p[5]; int fi[5]; };

__global__ void conv_w(W5 w, u16* __restrict__ out, const int* __restrict__ flags) {
  int wi = blockIdx.y;
  int f = flags[w.fi[wi]];
  size_t base = (size_t)wi * (CDIM * CDIM);
  int t = blockIdx.x * blockDim.x + threadIdx.x;   // 0 .. CDIM*CDIM/8-1
  size_t e = (size_t)t * 8;
  if (f) {
    const float4* in = (const float4*)w.p[wi];
    float4 a0 = in[t * 2], a1 = in[t * 2 + 1];
    __align__(16) u16 tmp[8];
    tmp[0] = f2bf(san(a0.x)); tmp[1] = f2bf(san(a0.y));
    tmp[2] = f2bf(san(a0.z)); tmp[3] = f2bf(san(a0.w));
    tmp[4] = f2bf(san(a1.x)); tmp[5] = f2bf(san(a1.y));
    tmp[6] = f2bf(san(a1.z)); tmp[7] = f2bf(san(a1.w));
    *(uint4*)&out[base + e] = *(uint4*)tmp;
  } else {
    const uint4* in = (const uint4*)w.p[wi];
    *(uint4*)&out[base + e] = in[t];
  }
}

// ---------------- transpose + zero-pad (dtype-flagged input -> bf16) ----
__global__ void transpose_pad(const void* __restrict__ inv, u16* __restrict__ out,
                              int Lin, int Lout, const int* __restrict__ flags, int fidx) {
  __shared__ u16 t[32][33];
  int f = flags[fidx];
  int b = blockIdx.z;
  int l0 = blockIdx.x * 32, c0 = blockIdx.y * 32;
  int x = threadIdx.x, y = threadIdx.y;
  bool valid = (l0 < Lin);   // Lin % 32 == 0: whole tile valid or whole tile pad
  if (valid) {
    for (int r = 0; r < 4; r++) {
      size_t idx = ((size_t)b * CDIM + c0 + y * 4 + r) * Lin + l0 + x;
      t[y * 4 + r][x] = f2bf(ldin(inv, idx, f));
    }
  }
  __syncthreads();
  for (int r = 0; r < 4; r++) {
    int lr = l0 + y * 4 + r;
    out[((size_t)b * Lout + lr) * CDIM + c0 + x] = valid ? t[x][y * 4 + r] : (u16)0;
  }
}

// ---------------- bf16 MFMA GEMM with BN epilogue (m97 structure) ----------
#define BK 32

__global__ __launch_bounds__(256) void gemm_bn(
    const u16* __restrict__ Wb, const u16* __restrict__ XT, void* __restrict__ Out,
    const void* __restrict__ sc, const void* __restrict__ sh, int Lpad,
    const int* __restrict__ flags, int sci, int shi, int f32out) {
  __shared__ __align__(16) u16 As[128 * BK];
  __shared__ __align__(16) u16 Bs[128 * BK];
  const int K = 1024;
  int tid = threadIdx.x;
  int lane = tid & 63, wave = tid >> 6;
  int m0 = blockIdx.y * 128, n0 = blockIdx.x * 128;
  int wm = (wave >> 1) * 64, wn = (wave & 1) * 64;
  int srow = lane >> 2;
  int scol = (lane & 3) * 8;
  const u16* Ag = Wb + (size_t)(m0 + wave * 32 + srow) * K + scol;
  const u16* Bg = XT + (size_t)(n0 + wave * 32 + srow) * K + scol;
  u16* Asl = &As[(wave * 32 + srow) * BK + scol];
  u16* Bsl = &Bs[(wave * 32 + srow) * BK + scol];
  floatx4 acc[4][4] = {};
  for (int k0 = 0; k0 < K; k0 += BK) {
    __syncthreads();
#pragma unroll
    for (int i = 0; i < 2; i++) {
      gload16(Ag + (size_t)(i * 16) * K + k0, Asl + i * 16 * BK);
      gload16(Bg + (size_t)(i * 16) * K + k0, Bsl + i * 16 * BK);
    }
    __syncthreads();
    int lr = lane & 15, q8 = (lane >> 4) * 8;
    short8 af[4], bfr[4];
#pragma unroll
    for (int f = 0; f < 4; f++) {
      af[f]  = *(const short8*)&As[(wm + f * 16 + lr) * BK + q8];
      bfr[f] = *(const short8*)&Bs[(wn + f * 16 + lr) * BK + q8];
    }
#pragma unroll
    for (int i = 0; i < 4; i++)
#pragma unroll
      for (int j = 0; j < 4; j++)
        acc[i][j] = __builtin_amdgcn_mfma_f32_16x16x32_bf16(af[i], bfr[j], acc[i][j], 0, 0, 0);
  }
  int sf = flags[sci], hf = flags[shi];
  int colL = lane & 15, rq = (lane >> 4) * 4;
  int b = n0 / Lpad;
  int lb = n0 - b * Lpad;
#pragma unroll
  for (int i = 0; i < 4; i++) {
    int gr0 = m0 + wm + i * 16 + rq;
    float s0 = ldin(sc, gr0, sf),     h0 = ldin(sh, gr0, hf);
    float s1 = ldin(sc, gr0 + 1, sf), h1 = ldin(sh, gr0 + 1, hf);
    float s2 = ldin(sc, gr0 + 2, sf), h2 = ldin(sh, gr0 + 2, hf);
    float s3 = ldin(sc, gr0 + 3, sf), h3 = ldin(sh, gr0 + 3, hf);
#pragma unroll
    for (int j = 0; j < 4; j++) {
      int gc = lb + wn + j * 16 + colL;
      size_t base = ((size_t)b * CDIM + gr0) * Lpad + gc;
      float r0 = acc[i][j][0] * s0 + h0;
      float r1 = acc[i][j][1] * s1 + h1;
      float r2 = acc[i][j][2] * s2 + h2;
      float r3 = acc[i][j][3] * s3 + h3;
      if (f32out) {
        float* O = (float*)Out;
        O[base]                    = r0;
        O[base + (size_t)Lpad]     = r1;
        O[base + 2 * (size_t)Lpad] = r2;
        O[base + 3 * (size_t)Lpad] = r3;
      } else {
        u16* O = (u16*)Out;
        O[base]                    = f2bf(r0);
        O[base + (size_t)Lpad]     = f2bf(r1);
        O[base + 2 * (size_t)Lpad] = f2bf(r2);
        O[base + 3 * (size_t)Lpad] = f2bf(r3);
      }
    }
  }
}

// ---------------- attention P precompute ----------------
// P slot stride padded to 16B multiple: base2 -> 4 floats, base3 -> 12 floats.
template<int BASE>
__global__ void p_compute(const u16* __restrict__ qk, float* __restrict__ P,
                          int Lstride, int n, int G) {
  constexpr int PSTR = (BASE == 2) ? 4 : 12;
  int lev = blockIdx.y;
  int t = blockIdx.x * blockDim.x + threadIdx.x;
  if (t >= 32 * G) return;
  int g = t % G, bh = t / G;
  int inner = 1;
  for (int i = 0; i < n - 1 - lev; i++) inner *= BASE;
  int ii = g / inner, kk = g - ii * inner;
  const u16* qp = qk + ((size_t)bh * 128) * Lstride;
  const u16* kp = qk + ((size_t)bh * 128 + 64) * Lstride;
  int lpos[BASE];
#pragma unroll
  for (int j = 0; j < BASE; j++) lpos[j] = (ii * BASE + j) * inner + kk;
  float S[BASE][BASE];
#pragma unroll
  for (int J = 0; J < BASE; J++)
#pragma unroll
    for (int j = 0; j < BASE; j++) S[J][j] = 0.f;
  for (int d = 0; d < 64; d++) {
    float qv[BASE], kv[BASE];
#pragma unroll
    for (int j = 0; j < BASE; j++) {
      qv[j] = bf2f(qp[(size_t)d * Lstride + lpos[j]]);
      kv[j] = bf2f(kp[(size_t)d * Lstride + lpos[j]]);
    }
#pragma unroll
    for (int J = 0; J < BASE; J++)
#pragma unroll
      for (int j = 0; j < BASE; j++) S[J][j] += kv[J] * qv[j];
  }
  float* Pg = P + ((size_t)lev * 32 * G + t) * PSTR;
#pragma unroll
  for (int J = 0; J < BASE; J++) {
    float mx = -1e30f;
#pragma unroll
    for (int j = 0; j < BASE; j++) { S[J][j] *= 0.125f; mx = fmaxf(mx, S[J][j]); }
    float e[BASE]; float sum = 0.f;
#pragma unroll
    for (int j = 0; j < BASE; j++) { e[j] = __expf(S[J][j] - mx); sum += e[j]; }
    float inv = 1.f / sum;
#pragma unroll
    for (int j = 0; j < BASE; j++) Pg[J * BASE + j] = e[j] * inv;
  }
}

// ---------------- in-LDS level apply, 4 rows per block ----------------
// LDS layout: Wl[pos*4 + r] bf16 (r = row within the 4-row batch).
// One P load per group feeds 4 rows (b64 LDS ops). Groups thread-disjoint.
template<int B, int N, int p>
__device__ __forceinline__ void lds_group(u16* __restrict__ Wl,
                                          const float* __restrict__ Pl, int g) {
  constexpr int inner = cipow(B, p);
  constexpr int PSTR = (B == 2) ? 4 : 12;
  int ii = g / inner, kk = g - ii * inner;
  int base = ii * (B * inner) + kk;
  const float4* Pg = (const float4*)(Pl + (size_t)g * PSTR);
  if constexpr (B == 2) {
    float4 pv = Pg[0];
    short4v a = *(short4v*)&Wl[base * 4];
    short4v b = *(short4v*)&Wl[(base + inner) * 4];
#pragma unroll
    for (int r = 0; r < 4; r++) {
      float i0 = bf2f((u16)a[r]), i1 = bf2f((u16)b[r]);
      a[r] = (short)f2bf(pv.x * i0 + pv.y * i1);
      b[r] = (short)f2bf(pv.z * i0 + pv.w * i1);
    }
    *(short4v*)&Wl[base * 4] = a;
    *(short4v*)&Wl[(base + inner) * 4] = b;
  } else {
    float4 A = Pg[0], Bv = Pg[1], Cv = Pg[2];
    short4v a = *(short4v*)&Wl[base * 4];
    short4v b = *(short4v*)&Wl[(base + inner) * 4];
    short4v c = *(short4v*)&Wl[(base + 2 * inner) * 4];
#pragma unroll
    for (int r = 0; r < 4; r++) {
      float i0 = bf2f((u16)a[r]), i1 = bf2f((u16)b[r]), i2 = bf2f((u16)c[r]);
      a[r] = (short)f2bf(A.x  * i0 + A.y  * i1 + A.z  * i2);
      b[r] = (short)f2bf(A.w  * i0 + Bv.x * i1 + Bv.y * i2);
      c[r] = (short)f2bf(Bv.z * i0 + Bv.w * i1 + Cv.x * i2);
    }
    *(short4v*)&Wl[base * 4] = a;
    *(short4v*)&Wl[(base + inner) * 4] = b;
    *(short4v*)&Wl[(base + 2 * inner) * 4] = c;
  }
}

template<int B, int N, int p>
__device__ __forceinline__ void lds_level4(u16* __restrict__ Wl,
                                           const float* __restrict__ Pl) {
  constexpr int G = cipow(B, N) / B;
#pragma unroll
  for (int it = 0; it < G / 256; it++)
    lds_group<B, N, p>(Wl, Pl, it * 256 + (int)threadIdx.x);
  if constexpr ((G % 256) != 0) {
    int g = (G / 256) * 256 + (int)threadIdx.x;
    if (g < G) lds_group<B, N, p>(Wl, Pl, g);
  }
}

template<int B, int N, int p, bool up>
__device__ __forceinline__ void chain_rec4(u16* __restrict__ Wl,
                                           const float* __restrict__ Pb, int bh) {
  constexpr int G = cipow(B, N) / B;
  constexpr int PSTR = (B == 2) ? 4 : 12;
  constexpr size_t PLEV = (size_t)32 * G * PSTR;
  __syncthreads();
  lds_level4<B, N, p>(Wl, Pb + (size_t)(N - 1 - p) * PLEV + (size_t)bh * G * PSTR);
  if constexpr (up) {
    if constexpr (p + 1 < N) chain_rec4<B, N, p + 1, true>(Wl, Pb, bh);
  } else {
    if constexpr (p > 0) chain_rec4<B, N, p - 1, false>(Wl, Pb, bh);
  }
}

// ---------------- fused attention chains + combine (4 rows/block) --------
// Block handles rows row0..row0+3 (same bh). LDS holds the 4 rows bf16 in
// [pos][row] layout. Both chains computed in-LDS; epilogue
// y = x + v1 + v2 + BN(dwconv3(v0)) fused; chain-1 result in registers.
// xres may alias y (stage 3): thread reads its elems before writing them.
template<int BASE, int N, int LSTR>
__global__ __launch_bounds__(256, 2) void fused_chains(
    const u16* __restrict__ v0, const void* __restrict__ xres,
    const void* __restrict__ wpe, const void* __restrict__ spe,
    const void* __restrict__ bpe, u16* __restrict__ y,
    const float* __restrict__ Pb, const int* __restrict__ flags,
    int xfi, int wpi, int spi, int bpi) {
  constexpr int L = cipow(BASE, N);
  constexpr int LW = (L + 7) & ~7;          // positions loaded (mult of 8)
  __shared__ __align__(16) u16 Wl[LW * 4];
  // XCD swizzle: 1024 blocks % 8 == 0 -> bijective; blocks of one bh (32)
  // land on one XCD so the shared P set stays in a single L2.
  int cpx = (int)gridDim.x >> 3;
  int blk = ((int)blockIdx.x & 7) * cpx + ((int)blockIdx.x >> 3);
  int row0 = blk * 4;
  int bh = row0 >> 7;
  int tid = threadIdx.x;

  auto loadV = [&]() {
#pragma unroll 2
    for (int i = tid; i < (LW / 8) * 4; i += 256) {
      int r = i & 3, ch = i >> 2;
      short8 x = *(const short8*)&v0[(size_t)(row0 + r) * LSTR + ch * 8];
#pragma unroll
      for (int k = 0; k < 8; k++) Wl[(ch * 8 + k) * 4 + r] = (u16)x[k];
    }
  };

  loadV();
  __syncthreads();

  // ---- epilogue prep: acc = x + BN(dwconv3(v0)) (Wl pristine here) ----
  int c0 = row0 & (CDIM - 1);
  int xf = flags[xfi], wf = flags[wpi], sf = flags[spi], bfg = flags[bpi];
  int l0 = tid * 16;                        // output positions l0..l0+15
  float acc[4][16];
#pragma unroll
  for (int r = 0; r < 4; r++) {
    int cr = c0 + r;
    float w0 = ldin(wpe, (size_t)cr * 3, wf);
    float w1 = ldin(wpe, (size_t)cr * 3 + 1, wf);
    float w2 = ldin(wpe, (size_t)cr * 3 + 2, wf);
    float scv = ldin(spe, cr, sf), bcv = ldin(bpe, cr, bfg);
    float vcf[16];
#pragma unroll
    for (int k = 0; k < 16; k++) vcf[k] = bf2f(Wl[(l0 + k) * 4 + r]);
    float vml = (l0 > 0) ? bf2f(Wl[(l0 - 1) * 4 + r]) : 0.f;
    float vpr = (l0 + 16 < L) ? bf2f(Wl[(l0 + 16) * 4 + r]) : 0.f;
    size_t xb = (size_t)(row0 + r) * 4096 + l0;
    float xr[16];
    if (xf) {
      const float* X = (const float*)xres;
#pragma unroll
      for (int k = 0; k < 16; k += 4) {
        float4 x4 = *(const float4*)&X[xb + k];
        xr[k] = san(x4.x); xr[k + 1] = san(x4.y);
        xr[k + 2] = san(x4.z); xr[k + 3] = san(x4.w);
      }
    } else {
      const u16* X = (const u16*)xres;
#pragma unroll
      for (int k8 = 0; k8 < 2; k8++) {
        short8 x8 = *(const short8*)&X[xb + k8 * 8];
#pragma unroll
        for (int k = 0; k < 8; k++) xr[k8 * 8 + k] = bf2f((u16)x8[k]);
      }
    }
#pragma unroll
    for (int k = 0; k < 16; k++) {
      float vm = k ? vcf[k - 1] : vml;
      float vp = (k < 15) ? vcf[k + 1] : vpr;
      acc[r][k] = xr[k] + (w0 * vm + w1 * vcf[k] + w2 * vp) * scv + bcv;
    }
  }

  // ---- chain v1: digits ascending p = 0..N-1 (original i = N-1..0) ----
  chain_rec4<BASE, N, 0, true>(Wl, Pb, bh);
  __syncthreads();
#pragma unroll
  for (int r = 0; r < 4; r++)
#pragma unroll
    for (int k = 0; k < 16; k++) acc[r][k] += bf2f(Wl[(l0 + k) * 4 + r]);
  __syncthreads();                          // acc reads done before reload
  loadV();
  // ---- chain v2: digits descending p = N-1..0 (original i = 0..N-1) ----
  chain_rec4<BASE, N, N - 1, false>(Wl, Pb, bh);   // barrier inside covers loadV
  __syncthreads();
#pragma unroll
  for (int r = 0; r < 4; r++) {
    size_t xb = (size_t)(row0 + r) * 4096 + l0;
    short8 o0, o1;
#pragma unroll
    for (int k = 0; k < 8; k++) {
      o0[k] = (short)f2bf(acc[r][k] + bf2f(Wl[(l0 + k) * 4 + r]));
      o1[k] = (short)f2bf(acc[r][k + 8] + bf2f(Wl[(l0 + k + 8) * 4 + r]));
    }
    *(short8*)&y[xb] = o0;
    *(short8*)&y[xb + 8] = o1;
  }
}

extern "C" void kernel_launch(void* const* d_in, const int* in_sizes, int n_in,
                              void* d_out, int out_size, void* d_ws, size_t ws_size,
                              hipStream_t stream) {
  const int W = 4096;
  const int Ls2 = 4096;                 // stage2 stride == L2
  const int Ls3 = 6656;                 // stage3: stride (52*128), L3 = 6561
  const int G2 = 2048, G3 = 2187;       // groups per (b,H)
  const size_t S3e = (size_t)NB * CDIM * Ls3;   // 27,262,976 elements

  // Arena: 3 bf16 slots + flags + bf16 weight arena ≈ 174 MB.
  // Pbuf aliases slotA: xT is dead once both GEMMs have run (sequential
  // stream), and P is dead before the next transpose writes slotA again.
  char* p = (char*)d_ws;
  auto alloc = [&](size_t bytes) { char* r = p; p += (bytes + 255) & ~(size_t)255; return r; };
  u16* slotA = (u16*)alloc(S3e * 2);   // xT ; later aliased by Pbuf
  u16* slotB = (u16*)alloc(S3e * 2);   // qk
  u16* slotC = (u16*)alloc(S3e * 2);   // v0
  int* flags = (int*)alloc(64 * 4);
  u16* warena = (u16*)alloc((size_t)5 * CDIM * CDIM * 2);  // 5 bf16 weight copies
  float* Pbuf = (float*)slotA;         // max P: base3 = 8*32*2187*12*4 B = 33.6 MB
  (void)ws_size; (void)n_in; (void)out_size;

  // y2/y3 staging (bf16) lives in the front half of d_out.
  u16* ybuf = (u16*)d_out;

  // ---- dtype sniff (writes flags[0..21]; flags[22]=0 = bf16 sentinel) ----
  PtrArgs pa;
  for (int i = 0; i < 22; i++) { pa.p[i] = d_in[i]; pa.n[i] = in_sizes[i]; }
  detect_dtypes<<<23, 256, 0, stream>>>(pa, flags);
  const int BF = 22;  // sentinel flag index (bf16)

  // ---- pre-convert the 5 GEMM weights to bf16 arena (flag-driven) ----
  W5 w5;
  const int widx[5] = {1, 4, 10, 13, 19};
  for (int i = 0; i < 5; i++) { w5.p[i] = d_in[widx[i]]; w5.fi[i] = widx[i]; }
  conv_w<<<dim3(CDIM * CDIM / 8 / 256, 5), 256, 0, stream>>>(w5, warena, flags);
  u16* wb_qk2 = warena;
  u16* wb_v2  = warena + (size_t)1 * CDIM * CDIM;
  u16* wb_qk3 = warena + (size_t)2 * CDIM * CDIM;
  u16* wb_v3  = warena + (size_t)3 * CDIM * CDIM;
  u16* wb_pr  = warena + (size_t)4 * CDIM * CDIM;

  dim3 tb(32, 8);

  // ================= stage base=2 (n=12, L=4096, no pad) =================
  transpose_pad<<<dim3(Ls2 / 32, CDIM / 32, NB), tb, 0, stream>>>(d_in[0], slotA, W, Ls2, flags, 0);
  gemm_bn<<<dim3(NB * Ls2 / 128, CDIM / 128), 256, 0, stream>>>(
      wb_qk2, slotA, slotB, d_in[2], d_in[3], Ls2, flags, 2, 3, 0);
  gemm_bn<<<dim3(NB * Ls2 / 128, CDIM / 128), 256, 0, stream>>>(
      wb_v2, slotA, slotC, d_in[5], d_in[6], Ls2, flags, 5, 6, 0);
  p_compute<2><<<dim3((32 * G2 + 255) / 256, 12), 256, 0, stream>>>(slotB, Pbuf, Ls2, 12, G2);
  fused_chains<2, 12, 4096><<<NB * CDIM / 4, 256, 0, stream>>>(
      slotC, d_in[0], d_in[7], d_in[8], d_in[9], ybuf, Pbuf, flags, 0, 7, 8, 9);

  // ================= stage base=3 (n=8, L=6561, stride 6656) =================
  transpose_pad<<<dim3(Ls3 / 32, CDIM / 32, NB), tb, 0, stream>>>(ybuf, slotA, W, Ls3, flags, BF);
  gemm_bn<<<dim3(NB * Ls3 / 128, CDIM / 128), 256, 0, stream>>>(
      wb_qk3, slotA, slotB, d_in[11], d_in[12], Ls3, flags, 11, 12, 0);
  gemm_bn<<<dim3(NB * Ls3 / 128, CDIM / 128), 256, 0, stream>>>(
      wb_v3, slotA, slotC, d_in[14], d_in[15], Ls3, flags, 14, 15, 0);
  p_compute<3><<<dim3((32 * G3 + 255) / 256, 8), 256, 0, stream>>>(slotB, Pbuf, Ls3, 8, G3);
  fused_chains<3, 8, 6656><<<NB * CDIM / 4, 256, 0, stream>>>(
      slotC, ybuf, d_in[16], d_in[17], d_in[18], ybuf, Pbuf, flags, BF, 16, 17, 18);

  // ================= final projection (fp32 output!) =================
  transpose_pad<<<dim3(Ls2 / 32, CDIM / 32, NB), tb, 0, stream>>>(ybuf, slotA, W, Ls2, flags, BF);
  gemm_bn<<<dim3(NB * Ls2 / 128, CDIM / 128), 256, 0, stream>>>(
      wb_pr, slotA, d_out, d_in[20], d_in[21], Ls2, flags, 20, 21, 1);
}